// Round 8
// baseline (127.768 us; speedup 1.0000x reference)
//
#include <hip/hip_runtime.h>
#include <math.h>

#ifndef M_PI
#define M_PI 3.14159265358979323846
#endif

#define HOP 160
#define NBLK_MAX 1024
#define PSLOTS 1036   // per-block partial slots: 1028 R + 6 L + 2 chunk sums

__device__ __forceinline__ float wave_reduce(float v) {
    for (int off = 32; off > 0; off >>= 1) v += __shfl_down(v, off, 64);
    return v;
}

// 8-point complex DFT in registers, natural order, W8 = exp(-i*pi/4).
__device__ __forceinline__ void dft8(float* xr, float* xi) {
    const float s = 0.70710678118654752440f;
    float t0r = xr[0] + xr[4], t0i = xi[0] + xi[4];
    float t1r = xr[0] - xr[4], t1i = xi[0] - xi[4];
    float t2r = xr[2] + xr[6], t2i = xi[2] + xi[6];
    float t3r = xr[2] - xr[6], t3i = xi[2] - xi[6];
    float E0r = t0r + t2r, E0i = t0i + t2i;
    float E2r = t0r - t2r, E2i = t0i - t2i;
    float E1r = t1r + t3i, E1i = t1i - t3r;
    float E3r = t1r - t3i, E3i = t1i + t3r;
    float u0r = xr[1] + xr[5], u0i = xi[1] + xi[5];
    float u1r = xr[1] - xr[5], u1i = xi[1] - xi[5];
    float u2r = xr[3] + xr[7], u2i = xi[3] + xi[7];
    float u3r = xr[3] - xr[7], u3i = xi[3] - xi[7];
    float O0r = u0r + u2r, O0i = u0i + u2i;
    float O2r = u0r - u2r, O2i = u0i - u2i;
    float O1r = u1r + u3i, O1i = u1i - u3r;
    float O3r = u1r - u3i, O3i = u1i + u3r;
    float T1r = s * (O1r + O1i), T1i = s * (O1i - O1r);
    float T2r = O2i,             T2i = -O2r;
    float T3r = s * (O3i - O3r), T3i = -s * (O3r + O3i);
    xr[0] = E0r + O0r; xi[0] = E0i + O0i;
    xr[4] = E0r - O0r; xi[4] = E0i - O0i;
    xr[1] = E1r + T1r; xi[1] = E1i + T1i;
    xr[5] = E1r - T1r; xi[5] = E1i - T1i;
    xr[2] = E2r + T2r; xi[2] = E2i + T2i;
    xr[6] = E2r - T2r; xi[6] = E2i - T2i;
    xr[3] = E3r + T3r; xi[3] = E3i + T3i;
    xr[7] = E3r - T3r; xi[7] = E3i - T3i;
}

__device__ __forceinline__ void cmul_t(float& zr, float& zi, float tr, float ti) {
    float r = zr * tr - zi * ti;
    float i = zr * ti + zi * tr;
    zr = r; zi = i;
}

// striped SoA LDS map: complex slot i -> re at a, im at a+128 (256-float stripes)
__device__ __forceinline__ int stripe(int i) {
    return ((i >> 7) << 8) | (i & 127);
}

// ---------------- STFT (wave-local FFT, 2 frames in flight) + covariance ---
// Latency-bound fix (R7 counters): two independent frames per wave (A/B),
// stage-interleaved, private LDS buffer each, so LDS round-trip latency of
// one frame hides under the other's VALU/DS issue. wt=0 clamped-address
// padding for tails. No barriers in the frame loop.
__global__ __launch_bounds__(256) void stft_fft_kernel(
        const float* __restrict__ x0, const float* __restrict__ x1,
        float* __restrict__ partials,
        int T, int nframes, int fpb, int nblocks, int cs,
        float invS, float kslope)
{
    __shared__ float smem[8192];   // 4 waves x 2 frames x 1024; reduce overlay
    const int tid = threadIdx.x;
    const int w = tid >> 6, l = tid & 63;
    float* bufA = smem + w * 2048;
    float* bufB = bufA + 1024;
    const int n0 = l & 7, hi = l >> 3;
    const int pl = (64 - l) & 63;

    // ---- fused mean partial: disjoint chunk [b*cs, (b+1)*cs) ----
    float c0 = 0.f, c1 = 0.f;
    {
        int lo = blockIdx.x * cs;
        int hi2 = lo + cs; if (hi2 > T) hi2 = T;
        for (int i = lo + tid; i < hi2; i += 256) { c0 += x0[i]; c1 += x1[i]; }
        c0 = wave_reduce(c0); c1 = wave_reduce(c1);
        if (l == 0) { smem[2 * w] = c0; smem[2 * w + 1] = c1; }
    }
    __syncthreads();
    const float c0T = (smem[0] + smem[2]) + (smem[4] + smem[6]);
    const float c1T = (smem[1] + smem[3]) + (smem[5] + smem[7]);
    __syncthreads();

    // per-lane constants: window*(1/32768) and independent twiddle tables
    float winv[8];
#pragma unroll
    for (int j = 0; j < 8; ++j)
        winv[j] = (0.5f - 0.5f * cosf((float)(2.0 * M_PI / 512.0) * (float)(l + 64 * j)))
                  * (1.0f / 32768.0f);
    float t1r[8], t1i[8], t2r[8], t2i[8];
#pragma unroll
    for (int j = 0; j < 8; ++j) {
        sincosf((float)(-2.0 * M_PI / 64.0) * (float)(j * hi), &t1i[j], &t1r[j]);
        sincosf((float)(-2.0 * M_PI / 512.0) * (float)(j * l), &t2i[j], &t2r[j]);
    }

    float A[8];
    float Wr[5], Wi[5];
    float L0r = 0.f, L0i = 0.f, L7r = 0.f, L7i = 0.f;  // L[k=l], L[k=l+448]
#pragma unroll
    for (int r = 0; r < 8; ++r) A[r] = 0.f;
#pragma unroll
    for (int r = 0; r < 5; ++r) { Wr[r] = 0.f; Wi[r] = 0.f; }

    int f0 = blockIdx.x * fpb;
    int f1 = f0 + fpb; if (f1 > nframes) f1 = nframes;

    for (int fA = f0 + w; fA < f1; fA += 8) {
        int fB = fA + 4;
        bool liveB = (fB < f1);
        int fcB = liveB ? fB : fA;
        int baseA = fA * HOP;
        int baseB = fcB * HOP;
        float wtA = expf(fmaf(kslope, (float)fA, -2.0f)) * invS;
        float wtB = liveB ? expf(fmaf(kslope, (float)fB, -2.0f)) * invS : 0.f;

        float zrA[8], ziA[8], zrB[8], ziB[8];
        // ---- load + preproc (both frames; loads issue together) ----
#pragma unroll
        for (int j = 0; j < 8; ++j) {
            int t = baseA + l + 64 * j;
            int tp = t - 1;
            if (j == 0) tp = (tp < 0) ? 0 : tp;
            float d0 = fmaf(-0.97f, x0[tp], x0[t]);
            float d1 = fmaf(-0.97f, x1[tp], x1[t]);
            zrA[j] = d0 * winv[j];
            ziA[j] = d1 * winv[j];
        }
#pragma unroll
        for (int j = 0; j < 8; ++j) {
            int t = baseB + l + 64 * j;
            int tp = t - 1;
            if (j == 0) tp = (tp < 0) ? 0 : tp;
            float d0 = fmaf(-0.97f, x0[tp], x0[t]);
            float d1 = fmaf(-0.97f, x1[tp], x1[t]);
            zrB[j] = d0 * winv[j];
            ziB[j] = d1 * winv[j];
        }

        dft8(zrA, ziA);
        dft8(zrB, ziB);

        // ---- T1 stores (A then B; independent buffers) ----
#pragma unroll
        for (int k2 = 0; k2 < 8; ++k2) {
            int a = stripe((l ^ (k2 << 3)) + 64 * k2);
            bufA[a] = zrA[k2]; bufA[a + 128] = ziA[k2];
        }
#pragma unroll
        for (int k2 = 0; k2 < 8; ++k2) {
            int a = stripe((l ^ (k2 << 3)) + 64 * k2);
            bufB[a] = zrB[k2]; bufB[a + 128] = ziB[k2];
        }
        // ---- T1 read + twiddle + dft8, A while B's stores drain ----
#pragma unroll
        for (int j = 0; j < 8; ++j) {
            int a = stripe(n0 + 8 * (j ^ hi) + 64 * hi);
            zrA[j] = bufA[a]; ziA[j] = bufA[a + 128];
        }
#pragma unroll
        for (int j = 1; j < 8; ++j) cmul_t(zrA[j], ziA[j], t1r[j], t1i[j]);
        dft8(zrA, ziA);
#pragma unroll
        for (int j = 0; j < 8; ++j) {
            int a = stripe(n0 + 8 * (j ^ hi) + 64 * hi);
            zrB[j] = bufB[a]; ziB[j] = bufB[a + 128];
        }
#pragma unroll
        for (int j = 1; j < 8; ++j) cmul_t(zrB[j], ziB[j], t1r[j], t1i[j]);
        dft8(zrB, ziB);

        // ---- T2 stores ----
#pragma unroll
        for (int k1 = 0; k1 < 8; ++k1) {
            int a = stripe(hi + 8 * ((k1 ^ n0) + 8 * n0));
            bufA[a] = zrA[k1]; bufA[a + 128] = ziA[k1];
        }
#pragma unroll
        for (int k1 = 0; k1 < 8; ++k1) {
            int a = stripe(hi + 8 * ((k1 ^ n0) + 8 * n0));
            bufB[a] = zrB[k1]; bufB[a + 128] = ziB[k1];
        }
        // ---- T2 read + twiddle + dft8 ----
#pragma unroll
        for (int j = 0; j < 8; ++j) {
            int a = stripe(n0 + 8 * ((hi ^ j) + 8 * j));
            zrA[j] = bufA[a]; ziA[j] = bufA[a + 128];
        }
#pragma unroll
        for (int j = 1; j < 8; ++j) cmul_t(zrA[j], ziA[j], t2r[j], t2i[j]);
        dft8(zrA, ziA);
#pragma unroll
        for (int j = 0; j < 8; ++j) {
            int a = stripe(n0 + 8 * ((hi ^ j) + 8 * j));
            zrB[j] = bufB[a]; ziB[j] = bufB[a + 128];
        }
#pragma unroll
        for (int j = 1; j < 8; ++j) cmul_t(zrB[j], ziB[j], t2r[j], t2i[j]);
        dft8(zrB, ziB);

        // ---- accumulate A ----
#pragma unroll
        for (int r = 0; r < 8; ++r) {
            float u = fmaf(zrA[r], zrA[r], ziA[r] * ziA[r]);
            A[r] = fmaf(wtA, u, A[r]);
        }
        L0r = fmaf(wtA, zrA[0], L0r); L0i = fmaf(wtA, ziA[0], L0i);
        L7r = fmaf(wtA, zrA[7], L7r); L7i = fmaf(wtA, ziA[7], L7i);
#pragma unroll
        for (int r = 0; r < 4; ++r) {
            float br = __shfl(zrA[7 - r], pl, 64);
            float bi = __shfl(ziA[7 - r], pl, 64);
            if (l == 0) { br = zrA[(8 - r) & 7]; bi = ziA[(8 - r) & 7]; }
            float wr = fmaf(zrA[r], br, -(ziA[r] * bi));
            float wi = fmaf(zrA[r], bi, ziA[r] * br);
            Wr[r] = fmaf(wtA, wr, Wr[r]);
            Wi[r] = fmaf(wtA, wi, Wi[r]);
        }
        {
            float wr = fmaf(zrA[4], zrA[4], -(ziA[4] * ziA[4]));
            float wi = 2.f * zrA[4] * ziA[4];
            Wr[4] = fmaf(wtA, wr, Wr[4]);
            Wi[4] = fmaf(wtA, wi, Wi[4]);
        }
        // ---- accumulate B ----
#pragma unroll
        for (int r = 0; r < 8; ++r) {
            float u = fmaf(zrB[r], zrB[r], ziB[r] * ziB[r]);
            A[r] = fmaf(wtB, u, A[r]);
        }
        L0r = fmaf(wtB, zrB[0], L0r); L0i = fmaf(wtB, ziB[0], L0i);
        L7r = fmaf(wtB, zrB[7], L7r); L7i = fmaf(wtB, ziB[7], L7i);
#pragma unroll
        for (int r = 0; r < 4; ++r) {
            float br = __shfl(zrB[7 - r], pl, 64);
            float bi = __shfl(ziB[7 - r], pl, 64);
            if (l == 0) { br = zrB[(8 - r) & 7]; bi = ziB[(8 - r) & 7]; }
            float wr = fmaf(zrB[r], br, -(ziB[r] * bi));
            float wi = fmaf(zrB[r], bi, ziB[r] * br);
            Wr[r] = fmaf(wtB, wr, Wr[r]);
            Wi[r] = fmaf(wtB, wi, Wi[r]);
        }
        {
            float wr = fmaf(zrB[4], zrB[4], -(ziB[4] * ziB[4]));
            float wi = 2.f * zrB[4] * ziB[4];
            Wr[4] = fmaf(wtB, wr, Wr[4]);
            Wi[4] = fmaf(wtB, wi, Wi[4]);
        }
    }

    // form (uncorrected) R per lane
    float R00[4], R11[4], R01r[4], R01i[4];
#pragma unroll
    for (int r = 0; r < 4; ++r) {
        float ap = __shfl(A[7 - r], pl, 64);
        if (l == 0) ap = A[(8 - r) & 7];
        R00[r]  = 0.25f * (A[r] + ap + 2.f * Wr[r]);
        R11[r]  = 0.25f * (A[r] + ap - 2.f * Wr[r]);
        R01r[r] = 0.5f  * Wi[r];
        R01i[r] = 0.25f * (A[r] - ap);
    }

    // block-level reduce across 4 waves via LDS overlay [4][PSLOTS]
    __syncthreads();
    float (*red)[PSLOTS] = (float (*)[PSLOTS])smem;
#pragma unroll
    for (int r = 0; r < 4; ++r) {
        int k = l + 64 * r;
        red[w][0 * 257 + k] = R00[r];
        red[w][1 * 257 + k] = R11[r];
        red[w][2 * 257 + k] = R01r[r];
        red[w][3 * 257 + k] = R01i[r];
    }
    if (l == 0) {
        red[w][0 * 257 + 256] = 0.5f * (A[4] + Wr[4]);
        red[w][1 * 257 + 256] = 0.5f * (A[4] - Wr[4]);
        red[w][2 * 257 + 256] = 0.5f * Wi[4];
        red[w][3 * 257 + 256] = 0.f;
        red[w][1028] = L0r;           // L[0]
        red[w][1029] = L0i;
    }
    if (l == 1) {
        red[w][1030] = L0r;           // L[1]
        red[w][1031] = L0i;
    }
    if (l == 63) {
        red[w][1032] = L7r;           // L[511]
        red[w][1033] = L7i;
    }
    if (l == 2) { red[w][1034] = 0.f; red[w][1035] = 0.f; }
    __syncthreads();
    // block-contiguous partials: fully-coalesced 4.1KB store, no RMW lines
    for (int s = tid; s < PSLOTS; s += 256) {
        float v = (red[0][s] + red[1][s]) + (red[2][s] + red[3][s]);
        if (s == 1034) v = c0T;
        if (s == 1035) v = c1T;
        partials[(size_t)blockIdx.x * PSLOTS + s] = v;
    }
}

// ---------------- reduce partials over blocks ------------------------------
__global__ __launch_bounds__(256) void reduce_kernel(
        const float* __restrict__ partials, float* __restrict__ R, int nblocks)
{
    int s = blockIdx.x;   // 0..PSLOTS-1
    int tid = threadIdx.x, lane = tid & 63, w = tid >> 6;
    float v = 0.f;
    for (int i = tid; i < nblocks; i += 256) v += partials[(size_t)i * PSLOTS + s];
    __shared__ float red[4];
    v = wave_reduce(v);
    if (lane == 0) red[w] = v;
    __syncthreads();
    if (tid == 0) R[s] = (red[0] + red[1]) + (red[2] + red[3]);
}

// ---------------- per-angle MVDR scores (181 blocks x 1 wave) --------------
// Applies the exact mean correction to bins 0 and 1 using L[0],L[1],L[511]:
// Z_true[k] = Z[k] - d*F[k], F = FFT(hann) = {256@0, -128@1, -128@511},
// d = 0.03*(m0 + i*m1).
__global__ __launch_bounds__(64) void score_kernel(
        const float* __restrict__ R, float* __restrict__ scores,
        float Sw, float invT32768)
{
    int a = blockIdx.x;          // angle 0..180
    int l = threadIdx.x;         // lane 0..63

    float rad = (float)a * (float)(M_PI / 180.0);
    float tau = -(0.05f * cosf(rad)) / 343.0f;
    float t2  = (float)(2.0 * M_PI) * tau;

    float dr = 0.03f * R[1034] * invT32768;
    float di = 0.03f * R[1035] * invT32768;
    float dd  = dr * dr + di * di;        // |d|^2
    float d2r = dr * dr - di * di;        // (d^2)_r
    float d2i = 2.f * dr * di;            // (d^2)_i

    float fwsum = 0.f;
    float geo = 0.f, ari = 0.f;
    float m = -1e30f, se = 0.f, pe = 0.f;

    for (int q = 0; q < 5; ++q) {
        int kk = l + 64 * q;
        if (kk > 256) break;
        float R00  = R[0 * 257 + kk];
        float R11  = R[1 * 257 + kk];
        float R01r = R[2 * 257 + kk];
        float R01i = R[3 * 257 + kk];

        if (q == 0 && l == 0) {   // bin 0: F0 = 256, partner = itself
            float Lr = R[1028], Li = R[1029];
            float dA  = -512.f * (dr * Lr + di * Li) + 65536.f * dd * Sw;
            float dLr = dr * Lr - di * Li;
            float dLi = dr * Li + di * Lr;
            float dWr = -512.f * dLr + 65536.f * Sw * d2r;
            float dWi = -512.f * dLi + 65536.f * Sw * d2i;
            R00  += 0.5f * (dA + dWr);
            R11  += 0.5f * (dA - dWr);
            R01r += 0.5f * dWi;
            // R01i stays 0
        }
        if (q == 0 && l == 1) {   // bin 1: F1 = F511 = -128
            float L1r = R[1030], L1i = R[1031];
            float L5r = R[1032], L5i = R[1033];
            float dA1 = 256.f * (dr * L1r + di * L1i) + 16384.f * dd * Sw;
            float dA5 = 256.f * (dr * L5r + di * L5i) + 16384.f * dd * Sw;
            float Sr = L1r + L5r, Si = L1i + L5i;
            float dWr = 128.f * (dr * Sr - di * Si) + 16384.f * Sw * d2r;
            float dWi = 128.f * (dr * Si + di * Sr) + 16384.f * Sw * d2i;
            R00  += 0.25f * (dA1 + dA5 + 2.f * dWr);
            R11  += 0.25f * (dA1 + dA5 - 2.f * dWr);
            R01r += 0.5f  * dWi;
            R01i += 0.25f * (dA1 - dA5);
        }

        float trace = (R00 + R11) * 0.5f;
        float det = R00 * R11 - (R01r * R01r + R01i * R01i) + 1e-6f * trace;
        float inv_det = 1.0f / det;
        float Sd = (R11 + R00) * inv_det;
        float qr = -R01r * inv_det;
        float qi = -R01i * inv_det;

        float fq = 31.25f * (float)kk;
        float wl = 343.0f / (fq + 1e-6f);
        float sr = 0.05f / wl;
        float spatial = 1.0f / (1.0f + expf(-4.0f * (sr - 0.1f)));
        float dq = fq - (float)(16000.0 / 6.0);
        float fwq = 1.0f - expf(-(dq * dq) / (float)(2.0 * 4000.0 * 4000.0));
        float alias = (sr < 0.5f) ? 1.0f : expf(-2.0f * (sr - 0.5f) * (sr - 0.5f));
        float fw = spatial * fwq * alias;
        fwsum += fw;

        float cr, ci;
        sincosf(t2 * fq, &ci, &cr);
        float t  = qr * cr + qi * ci;
        float qf = Sd + t + t;
        float mv = 1.0f / (qf + 1e-6f);

        geo = fmaf(logf(mv + 1e-6f), fw, geo);
        ari = fmaf(mv, fw, ari);
        float x = mv + mv;
        if (x > m) {
            float sc = expf(m - x);
            se = fmaf(se, sc, 1.0f);
            pe = fmaf(pe, sc, mv * fw);
            m = x;
        } else {
            float e = expf(x - m);
            se += e;
            pe = fmaf(mv * fw, e, pe);
        }
    }

    for (int off = 1; off < 64; off <<= 1) {
        fwsum += __shfl_xor(fwsum, off, 64);
        geo   += __shfl_xor(geo, off, 64);
        ari   += __shfl_xor(ari, off, 64);
        float mo = __shfl_xor(m, off, 64);
        float so = __shfl_xor(se, off, 64);
        float po = __shfl_xor(pe, off, 64);
        float mm = fmaxf(m, mo);
        float e1 = expf(m - mm), e2 = expf(mo - mm);
        se = fmaf(se, e1, so * e2);
        pe = fmaf(pe, e1, po * e2);
        m = mm;
    }
    if (l == 0) {
        float invcw = 1.0f / (fwsum + 1e-6f);
        float geon = geo * invcw;
        float arin = ari * invcw;
        float peak = (pe * invcw) / se;
        scores[a] = 0.5f * expf(geon) + 0.3f * arin + 0.2f * peak;
    }
}

// ---------------- argmax over 181 scores -----------------------------------
__global__ __launch_bounds__(256) void argmax_kernel(
        const float* __restrict__ scores, float* __restrict__ out)
{
    int tid = threadIdx.x, lane = tid & 63, w = tid >> 6;
    float v = (tid < 181) ? scores[tid] : -1e30f;
    int   i = tid;
    for (int off = 1; off < 64; off <<= 1) {
        float vo = __shfl_xor(v, off, 64);
        int   io = __shfl_xor(i, off, 64);
        if (vo > v || (vo == v && io < i)) { v = vo; i = io; }
    }
    __shared__ float rv[4];
    __shared__ int   ri[4];
    if (lane == 0) { rv[w] = v; ri[w] = i; }
    __syncthreads();
    if (tid == 0) {
        float bv = rv[0]; int bi = ri[0];
        for (int q = 1; q < 4; ++q) {
            if (rv[q] > bv || (rv[q] == bv && ri[q] < bi)) { bv = rv[q]; bi = ri[q]; }
        }
        out[0] = (float)bi;
    }
}

extern "C" void kernel_launch(void* const* d_in, const int* in_sizes, int n_in,
                              void* d_out, int out_size, void* d_ws, size_t ws_size,
                              hipStream_t stream) {
    const float* x0 = (const float*)d_in[0];
    const float* x1 = (const float*)d_in[1];
    float* out = (float*)d_out;
    int T = in_sizes[0];
    int nframes = (T - 512) / HOP + 1;

    // TEMPORAL weights: total sum and first-nframes sum (host, double)
    double Stot = 0.0, Spart = 0.0;
    for (int j = 0; j < 40000; ++j) {
        double e = exp(-2.0 + 2.0 * (double)j / 39999.0);
        Stot += e;
        if (j < nframes) Spart += e;
    }
    float invS = (float)(1.0 / Stot);
    float kslope = (float)(2.0 / 39999.0);
    float Sw = (float)(Spart / Stot);
    float invT32768 = (float)(1.0 / ((double)T * 32768.0));

    float* ws = (float*)d_ws;
    float* Rbuf     = ws;            // PSLOTS
    float* scores   = ws + 2048;     // 181
    float* partials = ws + 4096;     // nblocks * PSLOTS (block-contiguous)

    long availf = (long)(ws_size / 4) - 4096;
    int nblocks = (int)(availf / PSLOTS);
    if (nblocks > NBLK_MAX) nblocks = NBLK_MAX;
    if (nblocks < 1) nblocks = 1;
    int fpb = (nframes + nblocks - 1) / nblocks;
    int cs  = (T + nblocks - 1) / nblocks;

    stft_fft_kernel<<<nblocks, 256, 0, stream>>>(x0, x1, partials,
                                                 T, nframes, fpb, nblocks, cs,
                                                 invS, kslope);
    reduce_kernel<<<PSLOTS, 256, 0, stream>>>(partials, Rbuf, nblocks);
    score_kernel<<<181, 64, 0, stream>>>(Rbuf, scores, Sw, invT32768);
    argmax_kernel<<<1, 256, 0, stream>>>(scores, out);
}

// Round 9
// 70.037 us; speedup vs baseline: 1.8243x; 1.8243x over previous
//
#include <hip/hip_runtime.h>
#include <math.h>

#ifndef M_PI
#define M_PI 3.14159265358979323846
#endif

#define HOP 160
#define NBLK_MAX 2048
#define PSLOTS 1036   // per-block partial slots: 1028 R + 6 L + 2 chunk sums

__device__ __forceinline__ float wave_reduce(float v) {
    for (int off = 32; off > 0; off >>= 1) v += __shfl_down(v, off, 64);
    return v;
}

// 8-point complex DFT in registers, natural order, W8 = exp(-i*pi/4).
__device__ __forceinline__ void dft8(float* xr, float* xi) {
    const float s = 0.70710678118654752440f;
    float t0r = xr[0] + xr[4], t0i = xi[0] + xi[4];
    float t1r = xr[0] - xr[4], t1i = xi[0] - xi[4];
    float t2r = xr[2] + xr[6], t2i = xi[2] + xi[6];
    float t3r = xr[2] - xr[6], t3i = xi[2] - xi[6];
    float E0r = t0r + t2r, E0i = t0i + t2i;
    float E2r = t0r - t2r, E2i = t0i - t2i;
    float E1r = t1r + t3i, E1i = t1i - t3r;
    float E3r = t1r - t3i, E3i = t1i + t3r;
    float u0r = xr[1] + xr[5], u0i = xi[1] + xi[5];
    float u1r = xr[1] - xr[5], u1i = xi[1] - xi[5];
    float u2r = xr[3] + xr[7], u2i = xi[3] + xi[7];
    float u3r = xr[3] - xr[7], u3i = xi[3] - xi[7];
    float O0r = u0r + u2r, O0i = u0i + u2i;
    float O2r = u0r - u2r, O2i = u0i - u2i;
    float O1r = u1r + u3i, O1i = u1i - u3r;
    float O3r = u1r - u3i, O3i = u1i + u3r;
    float T1r = s * (O1r + O1i), T1i = s * (O1i - O1r);
    float T2r = O2i,             T2i = -O2r;
    float T3r = s * (O3i - O3r), T3i = -s * (O3r + O3i);
    xr[0] = E0r + O0r; xi[0] = E0i + O0i;
    xr[4] = E0r - O0r; xi[4] = E0i - O0i;
    xr[1] = E1r + T1r; xi[1] = E1i + T1i;
    xr[5] = E1r - T1r; xi[5] = E1i - T1i;
    xr[2] = E2r + T2r; xi[2] = E2i + T2i;
    xr[6] = E2r - T2r; xi[6] = E2i - T2i;
    xr[3] = E3r + T3r; xi[3] = E3i + T3i;
    xr[7] = E3r - T3r; xi[7] = E3i - T3i;
}

__device__ __forceinline__ void cmul_t(float& zr, float& zi, float tr, float ti) {
    float r = zr * tr - zi * ti;
    float i = zr * ti + zi * tr;
    zr = r; zi = i;
}

// ---------------- STFT (wave-local FFT) + covariance + fused mean partials -
// Stride-72 padded LDS layout: every ds op is ONE loop-invariant base reg +
// compile-time immediate offset, and every phase is <=2 lanes/bank (free).
//   T1: L1(n0,n1,k2) = n0 + 8*n1 + 72*k2   (write base l, read base b1r)
//   T2: L2(k2,k1,n0) = k2 + 8*k1 + 72*n0   (write base b2w, read base l)
// im plane at +576 floats. Per-wave buffer 1152 floats (4.6 KB).
__global__ __launch_bounds__(256) void stft_fft_kernel(
        const float* __restrict__ x0, const float* __restrict__ x1,
        float* __restrict__ partials,
        int T, int nframes, int fpb, int nblocks, int cs,
        float invS, float kslope)
{
    __shared__ float smem[4608];   // 4 waves x 1152; reduce overlay 4x1036
    const int tid = threadIdx.x;
    const int w = tid >> 6, l = tid & 63;
    float* buf = smem + w * 1152;
    const int n0 = l & 7, hi = l >> 3;
    const int pl = (64 - l) & 63;
    const int b1r = n0 + 72 * hi;    // T1-read base
    const int b2w = hi + 72 * n0;    // T2-write base

    // ---- fused mean partial: disjoint chunk [b*cs, (b+1)*cs) ----
    float c0 = 0.f, c1 = 0.f;
    {
        int lo = blockIdx.x * cs;
        int hi2 = lo + cs; if (hi2 > T) hi2 = T;
        for (int i = lo + tid; i < hi2; i += 256) { c0 += x0[i]; c1 += x1[i]; }
        c0 = wave_reduce(c0); c1 = wave_reduce(c1);
        if (l == 0) { smem[2 * w] = c0; smem[2 * w + 1] = c1; }
    }
    __syncthreads();
    const float c0T = (smem[0] + smem[2]) + (smem[4] + smem[6]);
    const float c1T = (smem[1] + smem[3]) + (smem[5] + smem[7]);
    __syncthreads();

    // per-lane constants: window*(1/32768) and independent twiddle tables
    float winv[8];
#pragma unroll
    for (int j = 0; j < 8; ++j)
        winv[j] = (0.5f - 0.5f * cosf((float)(2.0 * M_PI / 512.0) * (float)(l + 64 * j)))
                  * (1.0f / 32768.0f);
    float t1r[8], t1i[8], t2r[8], t2i[8];
#pragma unroll
    for (int j = 0; j < 8; ++j) {
        sincosf((float)(-2.0 * M_PI / 64.0) * (float)(j * hi), &t1i[j], &t1r[j]);
        sincosf((float)(-2.0 * M_PI / 512.0) * (float)(j * l), &t2i[j], &t2r[j]);
    }

    float A[8];
    float Wr[5], Wi[5];
    float L0r = 0.f, L0i = 0.f, L7r = 0.f, L7i = 0.f;  // L[k=l], L[k=l+448]
#pragma unroll
    for (int r = 0; r < 8; ++r) A[r] = 0.f;
#pragma unroll
    for (int r = 0; r < 5; ++r) { Wr[r] = 0.f; Wi[r] = 0.f; }

    int f0 = blockIdx.x * fpb;
    int f1 = f0 + fpb; if (f1 > nframes) f1 = nframes;

    for (int f = f0 + w; f < f1; f += 4) {
        int base = f * HOP;
        float wt = expf(fmaf(kslope, (float)f, -2.0f)) * invS;

        float zr[8], zi[8];
#pragma unroll
        for (int j = 0; j < 8; ++j) {
            int t = base + l + 64 * j;
            int tp = t - 1;
            if (j == 0) tp = (tp < 0) ? 0 : tp;   // windowed to 0 at n=0 anyway
            float d0 = fmaf(-0.97f, x0[tp], x0[t]);
            float d1 = fmaf(-0.97f, x1[tp], x1[t]);
            zr[j] = d0 * winv[j];
            zi[j] = d1 * winv[j];
        }

        dft8(zr, zi);   // over n2 -> regs k2

        // T1 store: base l, imm 72*k2 (+576 im)
#pragma unroll
        for (int k2 = 0; k2 < 8; ++k2) {
            buf[l + 72 * k2] = zr[k2];
            buf[l + 72 * k2 + 576] = zi[k2];
        }
        // T1 read: base b1r, imm 8*j
#pragma unroll
        for (int j = 0; j < 8; ++j) {
            zr[j] = buf[b1r + 8 * j];
            zi[j] = buf[b1r + 8 * j + 576];
        }
#pragma unroll
        for (int j = 1; j < 8; ++j) cmul_t(zr[j], zi[j], t1r[j], t1i[j]);  // W64^{n1*k2}
        dft8(zr, zi);   // over n1 -> regs k1

        // T2 store: base b2w, imm 8*k1
#pragma unroll
        for (int k1 = 0; k1 < 8; ++k1) {
            buf[b2w + 8 * k1] = zr[k1];
            buf[b2w + 8 * k1 + 576] = zi[k1];
        }
        // T2 read: base l, imm 72*j
#pragma unroll
        for (int j = 0; j < 8; ++j) {
            zr[j] = buf[l + 72 * j];
            zi[j] = buf[l + 72 * j + 576];
        }
#pragma unroll
        for (int j = 1; j < 8; ++j) cmul_t(zr[j], zi[j], t2r[j], t2i[j]);  // W512^{n0*l}
        dft8(zr, zi);   // over n0 -> Z[l + 64*k0] in regs k0

        // A_k += wt*|Z_k|^2 (all 8); linear accums for bins l (r=0), l+448 (r=7)
#pragma unroll
        for (int r = 0; r < 8; ++r) {
            float u = fmaf(zr[r], zr[r], zi[r] * zi[r]);
            A[r] = fmaf(wt, u, A[r]);
        }
        L0r = fmaf(wt, zr[0], L0r); L0i = fmaf(wt, zi[0], L0i);
        L7r = fmaf(wt, zr[7], L7r); L7i = fmaf(wt, zi[7], L7i);

        // W_k += wt * Z_k * Z_{512-k} for k = l+64r, r<4
#pragma unroll
        for (int r = 0; r < 4; ++r) {
            float br = __shfl(zr[7 - r], pl, 64);
            float bi = __shfl(zi[7 - r], pl, 64);
            if (l == 0) { br = zr[(8 - r) & 7]; bi = zi[(8 - r) & 7]; }
            float wr = fmaf(zr[r], br, -(zi[r] * bi));
            float wi = fmaf(zr[r], bi, zi[r] * br);
            Wr[r] = fmaf(wt, wr, Wr[r]);
            Wi[r] = fmaf(wt, wi, Wi[r]);
        }
        {   // Nyquist bin 256 (lane 0's reg 4)
            float wr = fmaf(zr[4], zr[4], -(zi[4] * zi[4]));
            float wi = 2.f * zr[4] * zi[4];
            Wr[4] = fmaf(wt, wr, Wr[4]);
            Wi[4] = fmaf(wt, wi, Wi[4]);
        }
    }

    // form (uncorrected) R per lane
    float R00[4], R11[4], R01r[4], R01i[4];
#pragma unroll
    for (int r = 0; r < 4; ++r) {
        float ap = __shfl(A[7 - r], pl, 64);
        if (l == 0) ap = A[(8 - r) & 7];
        R00[r]  = 0.25f * (A[r] + ap + 2.f * Wr[r]);
        R11[r]  = 0.25f * (A[r] + ap - 2.f * Wr[r]);
        R01r[r] = 0.5f  * Wi[r];
        R01i[r] = 0.25f * (A[r] - ap);
    }

    // block-level reduce across 4 waves via LDS overlay [4][PSLOTS]
    __syncthreads();
    float (*red)[PSLOTS] = (float (*)[PSLOTS])smem;
#pragma unroll
    for (int r = 0; r < 4; ++r) {
        int k = l + 64 * r;
        red[w][0 * 257 + k] = R00[r];
        red[w][1 * 257 + k] = R11[r];
        red[w][2 * 257 + k] = R01r[r];
        red[w][3 * 257 + k] = R01i[r];
    }
    if (l == 0) {
        red[w][0 * 257 + 256] = 0.5f * (A[4] + Wr[4]);
        red[w][1 * 257 + 256] = 0.5f * (A[4] - Wr[4]);
        red[w][2 * 257 + 256] = 0.5f * Wi[4];
        red[w][3 * 257 + 256] = 0.f;
        red[w][1028] = L0r;           // L[0]
        red[w][1029] = L0i;
    }
    if (l == 1) {
        red[w][1030] = L0r;           // L[1]
        red[w][1031] = L0i;
    }
    if (l == 63) {
        red[w][1032] = L7r;           // L[511]
        red[w][1033] = L7i;
    }
    if (l == 2) { red[w][1034] = 0.f; red[w][1035] = 0.f; }
    __syncthreads();
    // block-contiguous partials: fully-coalesced 4.1KB store, no RMW lines
    for (int s = tid; s < PSLOTS; s += 256) {
        float v = (red[0][s] + red[1][s]) + (red[2][s] + red[3][s]);
        if (s == 1034) v = c0T;
        if (s == 1035) v = c1T;
        partials[(size_t)blockIdx.x * PSLOTS + s] = v;
    }
}

// ---------------- reduce partials over blocks ------------------------------
__global__ __launch_bounds__(256) void reduce_kernel(
        const float* __restrict__ partials, float* __restrict__ R, int nblocks)
{
    int s = blockIdx.x;   // 0..PSLOTS-1
    int tid = threadIdx.x, lane = tid & 63, w = tid >> 6;
    float v = 0.f;
    for (int i = tid; i < nblocks; i += 256) v += partials[(size_t)i * PSLOTS + s];
    __shared__ float red[4];
    v = wave_reduce(v);
    if (lane == 0) red[w] = v;
    __syncthreads();
    if (tid == 0) R[s] = (red[0] + red[1]) + (red[2] + red[3]);
}

// ---------------- per-angle MVDR scores (181 blocks x 1 wave) --------------
// Applies the exact mean correction to bins 0 and 1 using L[0],L[1],L[511]:
// Z_true[k] = Z[k] - d*F[k], F = FFT(hann) = {256@0, -128@1, -128@511},
// d = 0.03*(m0 + i*m1).
__global__ __launch_bounds__(64) void score_kernel(
        const float* __restrict__ R, float* __restrict__ scores,
        float Sw, float invT32768)
{
    int a = blockIdx.x;          // angle 0..180
    int l = threadIdx.x;         // lane 0..63

    float rad = (float)a * (float)(M_PI / 180.0);
    float tau = -(0.05f * cosf(rad)) / 343.0f;
    float t2  = (float)(2.0 * M_PI) * tau;

    float dr = 0.03f * R[1034] * invT32768;
    float di = 0.03f * R[1035] * invT32768;
    float dd  = dr * dr + di * di;        // |d|^2
    float d2r = dr * dr - di * di;        // (d^2)_r
    float d2i = 2.f * dr * di;            // (d^2)_i

    float fwsum = 0.f;
    float geo = 0.f, ari = 0.f;
    float m = -1e30f, se = 0.f, pe = 0.f;

    for (int q = 0; q < 5; ++q) {
        int kk = l + 64 * q;
        if (kk > 256) break;
        float R00  = R[0 * 257 + kk];
        float R11  = R[1 * 257 + kk];
        float R01r = R[2 * 257 + kk];
        float R01i = R[3 * 257 + kk];

        if (q == 0 && l == 0) {   // bin 0: F0 = 256, partner = itself
            float Lr = R[1028], Li = R[1029];
            float dA  = -512.f * (dr * Lr + di * Li) + 65536.f * dd * Sw;
            float dLr = dr * Lr - di * Li;
            float dLi = dr * Li + di * Lr;
            float dWr = -512.f * dLr + 65536.f * Sw * d2r;
            float dWi = -512.f * dLi + 65536.f * Sw * d2i;
            R00  += 0.5f * (dA + dWr);
            R11  += 0.5f * (dA - dWr);
            R01r += 0.5f * dWi;
            // R01i stays 0
        }
        if (q == 0 && l == 1) {   // bin 1: F1 = F511 = -128
            float L1r = R[1030], L1i = R[1031];
            float L5r = R[1032], L5i = R[1033];
            float dA1 = 256.f * (dr * L1r + di * L1i) + 16384.f * dd * Sw;
            float dA5 = 256.f * (dr * L5r + di * L5i) + 16384.f * dd * Sw;
            float Sr = L1r + L5r, Si = L1i + L5i;
            float dWr = 128.f * (dr * Sr - di * Si) + 16384.f * Sw * d2r;
            float dWi = 128.f * (dr * Si + di * Sr) + 16384.f * Sw * d2i;
            R00  += 0.25f * (dA1 + dA5 + 2.f * dWr);
            R11  += 0.25f * (dA1 + dA5 - 2.f * dWr);
            R01r += 0.5f  * dWi;
            R01i += 0.25f * (dA1 - dA5);
        }

        float trace = (R00 + R11) * 0.5f;
        float det = R00 * R11 - (R01r * R01r + R01i * R01i) + 1e-6f * trace;
        float inv_det = 1.0f / det;
        float Sd = (R11 + R00) * inv_det;
        float qr = -R01r * inv_det;
        float qi = -R01i * inv_det;

        float fq = 31.25f * (float)kk;
        float wl = 343.0f / (fq + 1e-6f);
        float sr = 0.05f / wl;
        float spatial = 1.0f / (1.0f + expf(-4.0f * (sr - 0.1f)));
        float dq = fq - (float)(16000.0 / 6.0);
        float fwq = 1.0f - expf(-(dq * dq) / (float)(2.0 * 4000.0 * 4000.0));
        float alias = (sr < 0.5f) ? 1.0f : expf(-2.0f * (sr - 0.5f) * (sr - 0.5f));
        float fw = spatial * fwq * alias;
        fwsum += fw;

        float cr, ci;
        sincosf(t2 * fq, &ci, &cr);
        float t  = qr * cr + qi * ci;
        float qf = Sd + t + t;
        float mv = 1.0f / (qf + 1e-6f);

        geo = fmaf(logf(mv + 1e-6f), fw, geo);
        ari = fmaf(mv, fw, ari);
        float x = mv + mv;
        if (x > m) {
            float sc = expf(m - x);
            se = fmaf(se, sc, 1.0f);
            pe = fmaf(pe, sc, mv * fw);
            m = x;
        } else {
            float e = expf(x - m);
            se += e;
            pe = fmaf(mv * fw, e, pe);
        }
    }

    for (int off = 1; off < 64; off <<= 1) {
        fwsum += __shfl_xor(fwsum, off, 64);
        geo   += __shfl_xor(geo, off, 64);
        ari   += __shfl_xor(ari, off, 64);
        float mo = __shfl_xor(m, off, 64);
        float so = __shfl_xor(se, off, 64);
        float po = __shfl_xor(pe, off, 64);
        float mm = fmaxf(m, mo);
        float e1 = expf(m - mm), e2 = expf(mo - mm);
        se = fmaf(se, e1, so * e2);
        pe = fmaf(pe, e1, po * e2);
        m = mm;
    }
    if (l == 0) {
        float invcw = 1.0f / (fwsum + 1e-6f);
        float geon = geo * invcw;
        float arin = ari * invcw;
        float peak = (pe * invcw) / se;
        scores[a] = 0.5f * expf(geon) + 0.3f * arin + 0.2f * peak;
    }
}

// ---------------- argmax over 181 scores -----------------------------------
__global__ __launch_bounds__(256) void argmax_kernel(
        const float* __restrict__ scores, float* __restrict__ out)
{
    int tid = threadIdx.x, lane = tid & 63, w = tid >> 6;
    float v = (tid < 181) ? scores[tid] : -1e30f;
    int   i = tid;
    for (int off = 1; off < 64; off <<= 1) {
        float vo = __shfl_xor(v, off, 64);
        int   io = __shfl_xor(i, off, 64);
        if (vo > v || (vo == v && io < i)) { v = vo; i = io; }
    }
    __shared__ float rv[4];
    __shared__ int   ri[4];
    if (lane == 0) { rv[w] = v; ri[w] = i; }
    __syncthreads();
    if (tid == 0) {
        float bv = rv[0]; int bi = ri[0];
        for (int q = 1; q < 4; ++q) {
            if (rv[q] > bv || (rv[q] == bv && ri[q] < bi)) { bv = rv[q]; bi = ri[q]; }
        }
        out[0] = (float)bi;
    }
}

extern "C" void kernel_launch(void* const* d_in, const int* in_sizes, int n_in,
                              void* d_out, int out_size, void* d_ws, size_t ws_size,
                              hipStream_t stream) {
    const float* x0 = (const float*)d_in[0];
    const float* x1 = (const float*)d_in[1];
    float* out = (float*)d_out;
    int T = in_sizes[0];
    int nframes = (T - 512) / HOP + 1;

    // TEMPORAL weights: total sum and first-nframes sum (host, double)
    double Stot = 0.0, Spart = 0.0;
    for (int j = 0; j < 40000; ++j) {
        double e = exp(-2.0 + 2.0 * (double)j / 39999.0);
        Stot += e;
        if (j < nframes) Spart += e;
    }
    float invS = (float)(1.0 / Stot);
    float kslope = (float)(2.0 / 39999.0);
    float Sw = (float)(Spart / Stot);
    float invT32768 = (float)(1.0 / ((double)T * 32768.0));

    float* ws = (float*)d_ws;
    float* Rbuf     = ws;            // PSLOTS
    float* scores   = ws + 2048;     // 181
    float* partials = ws + 4096;     // nblocks * PSLOTS (block-contiguous)

    long availf = (long)(ws_size / 4) - 4096;
    int nblocks = (int)(availf / PSLOTS);
    if (nblocks > NBLK_MAX) nblocks = NBLK_MAX;
    if (nblocks < 1) nblocks = 1;
    int fpb = (nframes + nblocks - 1) / nblocks;
    int cs  = (T + nblocks - 1) / nblocks;

    stft_fft_kernel<<<nblocks, 256, 0, stream>>>(x0, x1, partials,
                                                 T, nframes, fpb, nblocks, cs,
                                                 invS, kslope);
    reduce_kernel<<<PSLOTS, 256, 0, stream>>>(partials, Rbuf, nblocks);
    score_kernel<<<181, 64, 0, stream>>>(Rbuf, scores, Sw, invT32768);
    argmax_kernel<<<1, 256, 0, stream>>>(scores, out);
}